// Round 7
// baseline (440.519 us; speedup 1.0000x reference)
//
#include <hip/hip_runtime.h>
#include <hip/hip_bf16.h>
#include <stdint.h>

#define B_DIM 4
#define NKK 4096
#define NQQ 4096
#define DD 64
#define HH 256

typedef __attribute__((ext_vector_type(4))) float floatx4;
typedef __attribute__((ext_vector_type(2))) float floatx2;
typedef __attribute__((ext_vector_type(8))) short bf16x8;

__device__ __forceinline__ float fexp2(float x) { return __builtin_amdgcn_exp2f(x); }
__device__ __forceinline__ unsigned fbits(float x) { return __float_as_uint(x); }
__device__ __forceinline__ float bf2f(unsigned short u) { return __uint_as_float(((unsigned)u) << 16); }

// a - b on both packed halves in ONE VOP3P instruction (gfx950 has
// v_pk_add_f32 but no packed f32 max/abs -- abs lives on the consumer's
// input modifier).
__device__ __forceinline__ floatx2 pk_sub(floatx2 a, floatx2 b) {
  floatx2 d;
  asm("v_pk_add_f32 %0, %1, %2 neg_lo:[0,1] neg_hi:[0,1]" : "=v"(d) : "v"(a), "v"(b));
  return d;
}

// round-to-nearest-even split: x = h + l, h/l bf16, rel err ~2^-17
__device__ __forceinline__ void splitbf(float x, unsigned short& h, unsigned short& l) {
  unsigned u = fbits(x);
  unsigned hu = (u + 0x7fff + ((u >> 16) & 1)) & 0xffff0000u;
  h = (unsigned short)(hu >> 16);
  l = (unsigned short)(fbits(x - __uint_as_float(hu)) >> 16);
}

// f32 LDS tile row stride (floats): bank-start 4r mod 32, 8 consecutive rows
// (lane reindex: lane owns rows {g+8t}) -> 8 distinct bank-quads ->
// conflict-free b128 (verified round 4: 33.9M -> 2.85M conflicts).
#define FSTRIDE 68
#define FSTRIDE4 17

// ---------------------------------------------------------------------------
// Weight split prep.
// ---------------------------------------------------------------------------
__global__ __launch_bounds__(256) void wsplit_kernel(
    const float* __restrict__ W1a, const float* __restrict__ W2a, const float* __restrict__ W3a,
    const float* __restrict__ W1b, const float* __restrict__ W2b, const float* __restrict__ W3b,
    unsigned short* __restrict__ sp)
{
  int idx = blockIdx.x * 256 + threadIdx.x;       // 0..196607
  const int set = idx >= 98304;
  int r = idx - set * 98304;
  unsigned short* base = sp + (size_t)set * 196608;
  const float* src;
  unsigned short *dh, *dl;
  int j;
  if (r < 16384)      { src = set ? W1b : W1a; dh = base;          dl = base + 16384;  j = r; }
  else if (r < 81920) { src = set ? W2b : W2a; dh = base + 32768;  dl = base + 98304;  j = r - 16384; }
  else                { src = set ? W3b : W3a; dh = base + 163840; dl = base + 180224; j = r - 81920; }
  unsigned short h, l;
  splitbf(src[j], h, l);
  dh[j] = h; dl[j] = l;
}

// ---------------------------------------------------------------------------
// V pre-transpose: Vt[b][d][k] = bf16(V[b][k][d]).
// ---------------------------------------------------------------------------
__global__ __launch_bounds__(256) void vtrans_kernel(
    const float* __restrict__ V, unsigned short* __restrict__ Vt)
{
  __shared__ unsigned short t[64][80];
  const int tid = threadIdx.x;
  const int b = blockIdx.y;
  const int k0 = blockIdx.x * 64;
  const float4* V4 = (const float4*)V;
  {
    const int r = tid & 63;
    const int c4 = tid >> 6;
#pragma unroll
    for (int j = 0; j < 4; ++j) {
      float4 f = V4[((size_t)(b * NKK + k0 + r)) * 16 + c4 * 4 + j];
      const int d0 = c4 * 16 + j * 4;
      t[d0 + 0][r] = (unsigned short)(fbits(f.x) >> 16);
      t[d0 + 1][r] = (unsigned short)(fbits(f.y) >> 16);
      t[d0 + 2][r] = (unsigned short)(fbits(f.z) >> 16);
      t[d0 + 3][r] = (unsigned short)(fbits(f.w) >> 16);
    }
  }
  __syncthreads();
  {
    const int d = tid >> 2;
    const int kc = tid & 3;
    uint4 u0 = *(const uint4*)&t[d][kc * 16];
    uint4 u1 = *(const uint4*)&t[d][kc * 16 + 8];
    unsigned short* dst = Vt + ((size_t)(b * 64 + d)) * NKK + k0 + kc * 16;
    *(uint4*)dst = u0;
    *(uint4*)(dst + 8) = u1;
  }
}

// ---------------------------------------------------------------------------
// MLP on MFMA, split-bf16 (hh+lh+hl). 64 tokens/WG, 512 threads (8 waves).
// ---------------------------------------------------------------------------
#define HSTRIDE 264   // shorts; 528B = 132 dwords = 4 mod 32 -> 2-way (free)
__global__ __launch_bounds__(512, 1) void mlpmm_kernel(
    const float* __restrict__ KEY, const float* __restrict__ QUERY,
    const float* __restrict__ B1a, const float* __restrict__ B2a, const float* __restrict__ B3a,
    const float* __restrict__ B1b, const float* __restrict__ B2b, const float* __restrict__ B3b,
    const unsigned short* __restrict__ sp,
    float* __restrict__ Ks, float* __restrict__ Qs, float* __restrict__ Wo)
{
  __shared__ unsigned short Xh[64][72], Xl[64][72];             // 18 KB
  __shared__ unsigned short Hsh[64][HSTRIDE], Hsl[64][HSTRIDE]; // 66 KB
  const int tid = threadIdx.x;
  const int w = tid >> 6;        // 0..7
  const int lane = tid & 63;
  const int l15 = lane & 15;
  const int quad = lane >> 4;

  const int g = blockIdx.x;
  const float* X;
  float* outp;
  int mulx, t0;
  const unsigned short* wb;
  const float *b1, *b2, *b3;
  if (g < 256)      { X = KEY;   outp = Ks; mulx = 1; t0 = g * 64;         wb = sp;          b1 = B1a; b2 = B2a; b3 = B3a; }
  else if (g < 512) { X = QUERY; outp = Qs; mulx = 1; t0 = (g - 256) * 64; wb = sp;          b1 = B1a; b2 = B2a; b3 = B3a; }
  else              { X = QUERY; outp = Wo; mulx = 0; t0 = (g - 512) * 64; wb = sp + 196608; b1 = B1b; b2 = B2b; b3 = B3b; }
  const unsigned short* W1h = wb;
  const unsigned short* W1l = wb + 16384;
  const unsigned short* W2h = wb + 32768;
  const unsigned short* W2l = wb + 98304;
  const unsigned short* W3h = wb + 163840;
  const unsigned short* W3l = wb + 180224;

  // ---- stage X tile (64 rows), split to bf16 h/l ----
  {
    const int t = tid >> 3;
    const int c = (tid & 7) * 8;
    float4 a = *(const float4*)&X[(size_t)(t0 + t) * 64 + c];
    float4 b = *(const float4*)&X[(size_t)(t0 + t) * 64 + c + 4];
    float v[8] = {a.x, a.y, a.z, a.w, b.x, b.y, b.z, b.w};
    unsigned short hs[8], ls[8];
#pragma unroll
    for (int e = 0; e < 8; ++e) splitbf(v[e], hs[e], ls[e]);
    uint4 uh = make_uint4(hs[0] | ((unsigned)hs[1] << 16), hs[2] | ((unsigned)hs[3] << 16),
                          hs[4] | ((unsigned)hs[5] << 16), hs[6] | ((unsigned)hs[7] << 16));
    uint4 ul = make_uint4(ls[0] | ((unsigned)ls[1] << 16), ls[2] | ((unsigned)ls[3] << 16),
                          ls[4] | ((unsigned)ls[5] << 16), ls[6] | ((unsigned)ls[7] << 16));
    *(uint4*)&Xh[t][c] = uh;
    *(uint4*)&Xl[t][c] = ul;
  }
  __syncthreads();

  // ---- layer 1: [64x64] x [64->256] ----
  {
    floatx4 acc[4][2];
#pragma unroll
    for (int nb = 0; nb < 2; ++nb) {
      const float bias = b1[(w * 2 + nb) * 16 + l15];
#pragma unroll
      for (int mb = 0; mb < 4; ++mb) acc[mb][nb] = (floatx4){bias, bias, bias, bias};
    }
#pragma unroll
    for (int kb = 0; kb < 2; ++kb) {
      bf16x8 Ah[4], Al[4];
#pragma unroll
      for (int mb = 0; mb < 4; ++mb) {
        Ah[mb] = *(const bf16x8*)&Xh[mb * 16 + l15][kb * 32 + quad * 8];
        Al[mb] = *(const bf16x8*)&Xl[mb * 16 + l15][kb * 32 + quad * 8];
      }
#pragma unroll
      for (int nb = 0; nb < 2; ++nb) {
        const int n0 = (w * 2 + nb) * 16;
        bf16x8 Bh = *(const bf16x8*)&W1h[(size_t)(n0 + l15) * 64 + kb * 32 + quad * 8];
        bf16x8 Bl = *(const bf16x8*)&W1l[(size_t)(n0 + l15) * 64 + kb * 32 + quad * 8];
#pragma unroll
        for (int mb = 0; mb < 4; ++mb) {
          acc[mb][nb] = __builtin_amdgcn_mfma_f32_16x16x32_bf16(Ah[mb], Bh, acc[mb][nb], 0, 0, 0);
          acc[mb][nb] = __builtin_amdgcn_mfma_f32_16x16x32_bf16(Al[mb], Bh, acc[mb][nb], 0, 0, 0);
          acc[mb][nb] = __builtin_amdgcn_mfma_f32_16x16x32_bf16(Ah[mb], Bl, acc[mb][nb], 0, 0, 0);
        }
      }
    }
#pragma unroll
    for (int mb = 0; mb < 4; ++mb)
#pragma unroll
      for (int nb = 0; nb < 2; ++nb) {
        const int col = (w * 2 + nb) * 16 + l15;
#pragma unroll
        for (int r = 0; r < 4; ++r) {
          const int row = mb * 16 + quad * 4 + r;
          float v = fmaxf(acc[mb][nb][r], 0.0f);
          unsigned short h, l;
          splitbf(v, h, l);
          Hsh[row][col] = h;
          Hsl[row][col] = l;
        }
      }
  }
  __syncthreads();

  // ---- layer 2: [64x256] x [256->256] ----
  {
    floatx4 acc2[4][2];
#pragma unroll
    for (int nb = 0; nb < 2; ++nb) {
      const float bias = b2[(w * 2 + nb) * 16 + l15];
#pragma unroll
      for (int mb = 0; mb < 4; ++mb) acc2[mb][nb] = (floatx4){bias, bias, bias, bias};
    }
#pragma unroll
    for (int kb = 0; kb < 8; ++kb) {
      bf16x8 Ah[4], Al[4];
#pragma unroll
      for (int mb = 0; mb < 4; ++mb) {
        Ah[mb] = *(const bf16x8*)&Hsh[mb * 16 + l15][kb * 32 + quad * 8];
        Al[mb] = *(const bf16x8*)&Hsl[mb * 16 + l15][kb * 32 + quad * 8];
      }
#pragma unroll
      for (int nb = 0; nb < 2; ++nb) {
        const int n0 = (w * 2 + nb) * 16;
        bf16x8 Bh = *(const bf16x8*)&W2h[(size_t)(n0 + l15) * 256 + kb * 32 + quad * 8];
        bf16x8 Bl = *(const bf16x8*)&W2l[(size_t)(n0 + l15) * 256 + kb * 32 + quad * 8];
#pragma unroll
        for (int mb = 0; mb < 4; ++mb) {
          acc2[mb][nb] = __builtin_amdgcn_mfma_f32_16x16x32_bf16(Ah[mb], Bh, acc2[mb][nb], 0, 0, 0);
          acc2[mb][nb] = __builtin_amdgcn_mfma_f32_16x16x32_bf16(Al[mb], Bh, acc2[mb][nb], 0, 0, 0);
          acc2[mb][nb] = __builtin_amdgcn_mfma_f32_16x16x32_bf16(Ah[mb], Bl, acc2[mb][nb], 0, 0, 0);
        }
      }
    }
    __syncthreads();
#pragma unroll
    for (int mb = 0; mb < 4; ++mb)
#pragma unroll
      for (int nb = 0; nb < 2; ++nb) {
        const int col = (w * 2 + nb) * 16 + l15;
#pragma unroll
        for (int r = 0; r < 4; ++r) {
          const int row = mb * 16 + quad * 4 + r;
          float v = fmaxf(acc2[mb][nb][r], 0.0f);
          unsigned short h, l;
          splitbf(v, h, l);
          Hsh[row][col] = h;
          Hsl[row][col] = l;
        }
      }
  }
  __syncthreads();

  // ---- layer 3: [64x256] x [256->64] ----
  {
    const int mp = (w >> 2) * 2;
    const int n0 = (w & 3) * 16;
    const float bias = b3[n0 + l15];
    floatx4 acc3[2];
#pragma unroll
    for (int m = 0; m < 2; ++m) acc3[m] = (floatx4){bias, bias, bias, bias};
#pragma unroll
    for (int kb = 0; kb < 8; ++kb) {
      bf16x8 Ah[2], Al[2];
#pragma unroll
      for (int m = 0; m < 2; ++m) {
        Ah[m] = *(const bf16x8*)&Hsh[(mp + m) * 16 + l15][kb * 32 + quad * 8];
        Al[m] = *(const bf16x8*)&Hsl[(mp + m) * 16 + l15][kb * 32 + quad * 8];
      }
      bf16x8 Bh = *(const bf16x8*)&W3h[(size_t)(n0 + l15) * 256 + kb * 32 + quad * 8];
      bf16x8 Bl = *(const bf16x8*)&W3l[(size_t)(n0 + l15) * 256 + kb * 32 + quad * 8];
#pragma unroll
      for (int m = 0; m < 2; ++m) {
        acc3[m] = __builtin_amdgcn_mfma_f32_16x16x32_bf16(Ah[m], Bh, acc3[m], 0, 0, 0);
        acc3[m] = __builtin_amdgcn_mfma_f32_16x16x32_bf16(Al[m], Bh, acc3[m], 0, 0, 0);
        acc3[m] = __builtin_amdgcn_mfma_f32_16x16x32_bf16(Ah[m], Bl, acc3[m], 0, 0, 0);
      }
    }
#pragma unroll
    for (int m = 0; m < 2; ++m)
#pragma unroll
      for (int r = 0; r < 4; ++r) {
        const int row = (mp + m) * 16 + quad * 4 + r;
        const int col = n0 + l15;
        float v = acc3[m][r];
        if (mulx) v *= (bf2f(Xh[row][col]) + bf2f(Xl[row][col]));
        outp[(size_t)(t0 + row) * 64 + col] = v;
      }
  }
}

// ---------------------------------------------------------------------------
// Flash attention over L1-distance scores, P.V on MFMA.
// Round-7: vtB LDS tile removed (V B-frags loaded straight from global Vt,
// prefetched a full iteration ahead) and epilogue m/l bufs overlaid on dead
// psB -> LDS 75776 -> 54272 B -> 3 blocks/CU. Grid grows to 3/CU-worth via
// a 2-way key split (template ITERS=16, PARTIAL=true): each half emits
// un-normalized partials (M, L, O) merged by amerge_kernel. DIRECT fallback
// (ITERS=32, z=1) if ws is too small for partials.
// ---------------------------------------------------------------------------
template <int ITERS, bool PARTIAL>
__global__ __launch_bounds__(256, 3) void attn_kernel(
    const float* __restrict__ Ksg, const float* __restrict__ Qsg,
    const unsigned short* __restrict__ Vtg, const float* __restrict__ Wog,
    float* __restrict__ outp,
    float* __restrict__ Pm, float* __restrict__ Pl, float* __restrict__ PO)
{
  __shared__ float qsA[32 * FSTRIDE];           // 8704 B
  __shared__ float ksA[4][32 * FSTRIDE];        // 34816 B; reused as O-merge buf
  __shared__ unsigned short psB[4][32 * 40];    // 10240 B; epilogue: m/l overlay
  __shared__ float abA[4][32];                  // 512 B
  // total 54272 B -> 3 blocks/CU

  const int tid  = threadIdx.x;
  const int w    = tid >> 6;
  const int lane = tid & 63;
  const int lq   = lane >> 3;
  const int lk   = lane & 7;
  const int l15  = lane & 15;
  const int quad = lane >> 4;
  const int b    = blockIdx.y;
  const int qt   = blockIdx.x * 32;

  {
    const int row = tid >> 3;
    const int c0  = (tid & 7) * 2;
    const float4* Q4 = (const float4*)Qsg;
    float4 g0 = Q4[(size_t)(b * NQQ + qt + row) * 16 + c0];
    float4 g1 = Q4[(size_t)(b * NQQ + qt + row) * 16 + c0 + 1];
    *(float4*)&qsA[row * FSTRIDE + c0 * 4]     = g0;
    *(float4*)&qsA[row * FSTRIDE + c0 * 4 + 4] = g1;
  }
  __syncthreads();

  float m_i[4], l_i[4];
  floatx4 acc[2][4];
#pragma unroll
  for (int i = 0; i < 4; ++i) { m_i[i] = -3.0e38f; l_i[i] = 0.0f; }
#pragma unroll
  for (int mb = 0; mb < 2; ++mb)
#pragma unroll
    for (int nb = 0; nb < 4; ++nb)
#pragma unroll
      for (int r = 0; r < 4; ++r) acc[mb][nb][r] = 0.0f;

  const int kstart = (blockIdx.z * 4 + w) * (ITERS * 32);
  const float4* K4 = (const float4*)Ksg;
  const float NEG_HALF_LOG2E = -0.72134752044448170f;  // -0.5*log2(e)

  const int krow = (lane >> 4);
  const int kci  = lane & 15;

  // V B-frag global base: lane (quad,l15) of frag nb reads
  // Vt[b][nb*16+l15][k=kstart+it*32+quad*8 .. +8] (16B, L2-resident).
  const unsigned short* vg0 = Vtg + ((size_t)b * 64 + l15) * NKK + kstart + quad * 8;

  float4 kpre[8];
  uint4 vtpre[4];
#pragma unroll
  for (int c = 0; c < 8; ++c)
    kpre[c] = K4[(size_t)(b * NKK + kstart + c * 4 + krow) * 16 + kci];
#pragma unroll
  for (int nb = 0; nb < 4; ++nb)
    vtpre[nb] = *(const uint4*)(vg0 + (size_t)nb * 16 * NKK);

  const floatx4* qb = (const floatx4*)&qsA[lq * FSTRIDE];
  const floatx4* kb = (const floatx4*)&ksA[w][lk * FSTRIDE];

  for (int it = 0; it < ITERS; ++it) {
    // ---- store prefetched K tile -> LDS (wave-private, no barrier) ----
#pragma unroll
    for (int c = 0; c < 8; ++c)
      *(float4*)&ksA[w][(c * 4 + krow) * FSTRIDE + kci * 4] = kpre[c];

    // ---- prefetch next K tile ----
    {
      const int itn = (it + 1 < ITERS) ? it + 1 : it;
#pragma unroll
      for (int c = 0; c < 8; ++c)
        kpre[c] = K4[(size_t)(b * NKK + kstart + itn * 32 + c * 4 + krow) * 16 + kci];
    }

    // ---- score: s[i][j] = sum_d |Ks[lk+8j] - Qs[lq+8i]|, 1.5 VALU/dim ----
    float s[4][4];
#pragma unroll
    for (int i = 0; i < 4; ++i)
#pragma unroll
      for (int j = 0; j < 4; ++j) s[i][j] = 0.0f;

#pragma unroll
    for (int dc = 0; dc < 16; ++dc) {
      floatx4 qv[4], kv[4];
#pragma unroll
      for (int i = 0; i < 4; ++i) qv[i] = qb[i * (8 * FSTRIDE4) + dc];
#pragma unroll
      for (int j = 0; j < 4; ++j) kv[j] = kb[j * (8 * FSTRIDE4) + dc];
#pragma unroll
      for (int i = 0; i < 4; ++i) {
        const floatx2 qlo = qv[i].lo, qhi = qv[i].hi;
#pragma unroll
        for (int j = 0; j < 4; ++j) {
          floatx2 d0 = pk_sub(qlo, kv[j].lo);
          floatx2 d1 = pk_sub(qhi, kv[j].hi);
          s[i][j] += __builtin_fabsf(d0.x);
          s[i][j] += __builtin_fabsf(d0.y);
          s[i][j] += __builtin_fabsf(d1.x);
          s[i][j] += __builtin_fabsf(d1.y);
        }
      }
    }

    // ---- online softmax (base-2); row max via min(s); l per-lane ----
    float a_row[4];
#pragma unroll
    for (int i = 0; i < 4; ++i) {
      float smin = fminf(fminf(s[i][0], s[i][1]), fminf(s[i][2], s[i][3]));
      smin = fminf(smin, __shfl_xor(smin, 1));
      smin = fminf(smin, __shfl_xor(smin, 2));
      smin = fminf(smin, __shfl_xor(smin, 4));
      const float tmax = smin * smin * NEG_HALF_LOG2E;
      const float mn = fmaxf(m_i[i], tmax);
      a_row[i] = fexp2(m_i[i] - mn);
      m_i[i] = mn;
      float ps = 0.0f;
#pragma unroll
      for (int j = 0; j < 4; ++j) {
        const float sv = s[i][j];
        const float e = fexp2(fmaf(sv * NEG_HALF_LOG2E, sv, -mn));
        ps += e;
        psB[w][(lq + 8 * i) * 40 + lk + 8 * j] = (unsigned short)(fbits(e) >> 16);
      }
      l_i[i] = fmaf(l_i[i], a_row[i], ps);
    }
    if (lk == 0) {
#pragma unroll
      for (int i = 0; i < 4; ++i) abA[w][lq + 8 * i] = a_row[i];
    }

    // ---- P.V on MFMA (B-frags straight from prefetched registers) ----
    {
      bf16x8 afrag[2];
#pragma unroll
      for (int mb = 0; mb < 2; ++mb)
        afrag[mb] = *(const bf16x8*)&psB[w][(mb * 16 + l15) * 40 + quad * 8];

      const floatx4 arv0 = *(const floatx4*)&abA[w][quad * 4];
      const floatx4 arv1 = *(const floatx4*)&abA[w][16 + quad * 4];

#pragma unroll
      for (int nb = 0; nb < 4; ++nb) {
        bf16x8 bfrag = __builtin_bit_cast(bf16x8, vtpre[nb]);
        acc[0][nb] *= arv0;
        acc[1][nb] *= arv1;
        acc[0][nb] = __builtin_amdgcn_mfma_f32_16x16x32_bf16(afrag[0], bfrag, acc[0][nb], 0, 0, 0);
        acc[1][nb] = __builtin_amdgcn_mfma_f32_16x16x32_bf16(afrag[1], bfrag, acc[1][nb], 0, 0, 0);
      }
    }

    // ---- prefetch next V tile (used next iter; full iter of latency slack) ----
    {
      const int itn = (it + 1 < ITERS) ? it + 1 : it;
#pragma unroll
      for (int nb = 0; nb < 4; ++nb)
        vtpre[nb] = *(const uint4*)(vg0 + (size_t)nb * 16 * NKK + itn * 32);
    }
  }

  // ---- epilogue: reduce l across lk; publish m,l (overlay on psB[w]) + O ----
#pragma unroll
  for (int i = 0; i < 4; ++i) {
    float l = l_i[i];
    l += __shfl_xor(l, 1);
    l += __shfl_xor(l, 2);
    l += __shfl_xor(l, 4);
    l_i[i] = l;
  }
  float* ovl = (float*)&psB[w][0];   // psB[w] dead after last P.V (wave-private)
  if (lk == 0) {
#pragma unroll
    for (int i = 0; i < 4; ++i) {
      ovl[lq + 8 * i]      = m_i[i];
      ovl[32 + lq + 8 * i] = l_i[i];
    }
  }
#pragma unroll
  for (int mb = 0; mb < 2; ++mb)
#pragma unroll
    for (int nb = 0; nb < 4; ++nb)
#pragma unroll
      for (int r = 0; r < 4; ++r)
        ksA[w][(mb * 16 + quad * 4 + r) * 64 + nb * 16 + l15] = acc[mb][nb][r];
  __syncthreads();

  {
    const int q = tid >> 3;
    const int dbase = (tid & 7) * 8;
    const float m0 = ((const float*)&psB[0][0])[q];
    const float m1 = ((const float*)&psB[1][0])[q];
    const float m2 = ((const float*)&psB[2][0])[q];
    const float m3 = ((const float*)&psB[3][0])[q];
    const float M = fmaxf(fmaxf(m0, m1), fmaxf(m2, m3));
    const float s0 = fexp2(m0 - M), s1 = fexp2(m1 - M);
    const float s2v = fexp2(m2 - M), s3 = fexp2(m3 - M);
    const float L = ((const float*)&psB[0][0])[32 + q] * s0 +
                    ((const float*)&psB[1][0])[32 + q] * s1 +
                    ((const float*)&psB[2][0])[32 + q] * s2v +
                    ((const float*)&psB[3][0])[32 + q] * s3;
    if (PARTIAL) {
      const size_t p = (size_t)(blockIdx.z * 4 + b) * 128 + blockIdx.x;
      if (dbase == 0) { Pm[p * 32 + q] = M; Pl[p * 32 + q] = L; }
      float* dst = PO + p * 2048 + q * 64 + dbase;
#pragma unroll
      for (int c = 0; c < 8; ++c) {
        const int d = dbase + c;
        dst[c] = s0 * ksA[0][q * 64 + d] + s1 * ksA[1][q * 64 + d] +
                 s2v * ksA[2][q * 64 + d] + s3 * ksA[3][q * 64 + d];
      }
    } else {
      const float rL = 1.0f / L;
      const size_t gbase = (size_t)(b * NQQ + qt + q) * 64 + dbase;
#pragma unroll
      for (int c = 0; c < 8; ++c) {
        const int d = dbase + c;
        float o = s0 * ksA[0][q * 64 + d] + s1 * ksA[1][q * 64 + d] +
                  s2v * ksA[2][q * 64 + d] + s3 * ksA[3][q * 64 + d];
        outp[gbase + c] = o * rL * Wog[gbase + c];
      }
    }
  }
}

// ---------------------------------------------------------------------------
// Merge the 2 key-half partials: out = (w0 O0 + w1 O1)/L * Wo.
// ---------------------------------------------------------------------------
__global__ __launch_bounds__(256) void amerge_kernel(
    const float* __restrict__ Pm, const float* __restrict__ Pl,
    const float* __restrict__ PO, const float* __restrict__ Wog,
    float* __restrict__ outp)
{
  const int tid = threadIdx.x;
  const int qt = blockIdx.x;
  const int b = blockIdx.y;
  const int q = tid >> 3;
  const int dbase = (tid & 7) * 8;
  const size_t p0 = (size_t)b * 128 + qt;
  const size_t p1 = (size_t)(4 + b) * 128 + qt;
  const float m0 = Pm[p0 * 32 + q], m1 = Pm[p1 * 32 + q];
  const float l0 = Pl[p0 * 32 + q], l1 = Pl[p1 * 32 + q];
  const float M = fmaxf(m0, m1);
  const float w0 = fexp2(m0 - M), w1 = fexp2(m1 - M);
  const float rL = 1.0f / (w0 * l0 + w1 * l1);
  const float* o0 = PO + p0 * 2048 + q * 64 + dbase;
  const float* o1 = PO + p1 * 2048 + q * 64 + dbase;
  const size_t g = ((size_t)b * NQQ + qt * 32 + q) * 64 + dbase;
#pragma unroll
  for (int c = 0; c < 8; ++c)
    outp[g + c] = (w0 * o0[c] + w1 * o1[c]) * rL * Wog[g + c];
}

// ---------------------------------------------------------------------------
extern "C" void kernel_launch(void* const* d_in, const int* in_sizes, int n_in,
                              void* d_out, int out_size, void* d_ws, size_t ws_size,
                              hipStream_t stream) {
  (void)in_sizes; (void)n_in; (void)out_size;
  const float* KEY   = (const float*)d_in[0];
  const float* VALUE = (const float*)d_in[1];
  const float* QUERY = (const float*)d_in[2];
  const float* W1w = (const float*)d_in[3];
  const float* W1b = (const float*)d_in[4];
  const float* W2w = (const float*)d_in[5];
  const float* W2b = (const float*)d_in[6];
  const float* W3w = (const float*)d_in[7];
  const float* W3b = (const float*)d_in[8];
  const float* Wo1w = (const float*)d_in[9];
  const float* Wo1b = (const float*)d_in[10];
  const float* Wo2w = (const float*)d_in[11];
  const float* Wo2b = (const float*)d_in[12];
  const float* Wo3w = (const float*)d_in[13];
  const float* Wo3b = (const float*)d_in[14];

  float* ws = (float*)d_ws;
  const size_t tsz = (size_t)B_DIM * NKK * DD;  // 1,048,576 floats
  float* Ks = ws;
  float* Qs = ws + tsz;
  float* Wo = ws + 2 * tsz;
  unsigned short* Vtg = (unsigned short*)(ws + 3 * tsz);  // tsz ushorts (2 MB)
  unsigned short* sp  = Vtg + tsz;                        // 2x196608 ushorts
  float* Pm = ws + 3 * tsz + tsz / 2 + 196608;            // partial maxes
  float* Pl = Pm + 32768;
  float* PO = Pl + 32768;                                 // 2x4x128x2048 floats
  float* outf = (float*)d_out;

  const size_t ws_need = (size_t)(3 * tsz + tsz / 2 + 196608 + 2 * 32768 + 2097152) * 4;
  const bool partial = ws_size >= ws_need;   // deterministic across calls

  wsplit_kernel<<<dim3(768), 256, 0, stream>>>(W1w, W2w, W3w, Wo1w, Wo2w, Wo3w, sp);
  vtrans_kernel<<<dim3(NKK / 64, B_DIM), 256, 0, stream>>>(VALUE, Vtg);
  mlpmm_kernel<<<dim3(768), 512, 0, stream>>>(
      KEY, QUERY, W1b, W2b, W3b, Wo1b, Wo2b, Wo3b, sp, Ks, Qs, Wo);
  if (partial) {
    attn_kernel<16, true><<<dim3(NQQ / 32, B_DIM, 2), 256, 0, stream>>>(
        Ks, Qs, Vtg, Wo, outf, Pm, Pl, PO);
    amerge_kernel<<<dim3(NQQ / 32, B_DIM), 256, 0, stream>>>(Pm, Pl, PO, Wo, outf);
  } else {
    attn_kernel<32, false><<<dim3(NQQ / 32, B_DIM, 1), 256, 0, stream>>>(
        Ks, Qs, Vtg, Wo, outf, Pm, Pl, PO);
  }
}

// Round 8
// 412.605 us; speedup vs baseline: 1.0677x; 1.0677x over previous
//
#include <hip/hip_runtime.h>
#include <hip/hip_bf16.h>
#include <stdint.h>

#define B_DIM 4
#define NKK 4096
#define NQQ 4096
#define DD 64
#define HH 256

typedef __attribute__((ext_vector_type(4))) float floatx4;
typedef __attribute__((ext_vector_type(2))) float floatx2;
typedef __attribute__((ext_vector_type(8))) short bf16x8;

__device__ __forceinline__ float fexp2(float x) { return __builtin_amdgcn_exp2f(x); }
__device__ __forceinline__ unsigned fbits(float x) { return __float_as_uint(x); }
__device__ __forceinline__ float bf2f(unsigned short u) { return __uint_as_float(((unsigned)u) << 16); }

// a - b on both packed halves in ONE VOP3P instruction (gfx950 has
// v_pk_add_f32 but no packed f32 max/abs -- abs lives on the consumer's
// input modifier).
__device__ __forceinline__ floatx2 pk_sub(floatx2 a, floatx2 b) {
  floatx2 d;
  asm("v_pk_add_f32 %0, %1, %2 neg_lo:[0,1] neg_hi:[0,1]" : "=v"(d) : "v"(a), "v"(b));
  return d;
}

// round-to-nearest-even split: x = h + l, h/l bf16, rel err ~2^-17
__device__ __forceinline__ void splitbf(float x, unsigned short& h, unsigned short& l) {
  unsigned u = fbits(x);
  unsigned hu = (u + 0x7fff + ((u >> 16) & 1)) & 0xffff0000u;
  h = (unsigned short)(hu >> 16);
  l = (unsigned short)(fbits(x - __uint_as_float(hu)) >> 16);
}

// f32 LDS tile row stride (floats): bank-start 4r mod 32, 8 consecutive rows
// (lane reindex: lane owns rows {g+8t}) -> 8 distinct bank-quads ->
// conflict-free b128 (verified round 4: 33.9M -> 2.85M conflicts).
#define FSTRIDE 68
#define FSTRIDE4 17
// psB row stride in shorts: 36 -> 72 B = 18 dwords; 18r mod 32 is distinct for
// all 16 simultaneously-read rows (gcd(18,32)=2, period 16) -> conflict-free
// A-frag b128 reads. 40->36 saves exactly 1 KB -> LDS total 52 KB.
#define PSTRIDE 36

// ---------------------------------------------------------------------------
// Weight split prep.
// ---------------------------------------------------------------------------
__global__ __launch_bounds__(256) void wsplit_kernel(
    const float* __restrict__ W1a, const float* __restrict__ W2a, const float* __restrict__ W3a,
    const float* __restrict__ W1b, const float* __restrict__ W2b, const float* __restrict__ W3b,
    unsigned short* __restrict__ sp)
{
  int idx = blockIdx.x * 256 + threadIdx.x;       // 0..196607
  const int set = idx >= 98304;
  int r = idx - set * 98304;
  unsigned short* base = sp + (size_t)set * 196608;
  const float* src;
  unsigned short *dh, *dl;
  int j;
  if (r < 16384)      { src = set ? W1b : W1a; dh = base;          dl = base + 16384;  j = r; }
  else if (r < 81920) { src = set ? W2b : W2a; dh = base + 32768;  dl = base + 98304;  j = r - 16384; }
  else                { src = set ? W3b : W3a; dh = base + 163840; dl = base + 180224; j = r - 81920; }
  unsigned short h, l;
  splitbf(src[j], h, l);
  dh[j] = h; dl[j] = l;
}

// ---------------------------------------------------------------------------
// V pre-transpose: Vt[b][d][k] = bf16(V[b][k][d]).
// ---------------------------------------------------------------------------
__global__ __launch_bounds__(256) void vtrans_kernel(
    const float* __restrict__ V, unsigned short* __restrict__ Vt)
{
  __shared__ unsigned short t[64][80];
  const int tid = threadIdx.x;
  const int b = blockIdx.y;
  const int k0 = blockIdx.x * 64;
  const float4* V4 = (const float4*)V;
  {
    const int r = tid & 63;
    const int c4 = tid >> 6;
#pragma unroll
    for (int j = 0; j < 4; ++j) {
      float4 f = V4[((size_t)(b * NKK + k0 + r)) * 16 + c4 * 4 + j];
      const int d0 = c4 * 16 + j * 4;
      t[d0 + 0][r] = (unsigned short)(fbits(f.x) >> 16);
      t[d0 + 1][r] = (unsigned short)(fbits(f.y) >> 16);
      t[d0 + 2][r] = (unsigned short)(fbits(f.z) >> 16);
      t[d0 + 3][r] = (unsigned short)(fbits(f.w) >> 16);
    }
  }
  __syncthreads();
  {
    const int d = tid >> 2;
    const int kc = tid & 3;
    uint4 u0 = *(const uint4*)&t[d][kc * 16];
    uint4 u1 = *(const uint4*)&t[d][kc * 16 + 8];
    unsigned short* dst = Vt + ((size_t)(b * 64 + d)) * NKK + k0 + kc * 16;
    *(uint4*)dst = u0;
    *(uint4*)(dst + 8) = u1;
  }
}

// ---------------------------------------------------------------------------
// MLP on MFMA, split-bf16 (hh+lh+hl). 64 tokens/WG, 512 threads (8 waves).
// ---------------------------------------------------------------------------
#define HSTRIDE 264   // shorts; 528B = 132 dwords = 4 mod 32 -> 2-way (free)
__global__ __launch_bounds__(512, 1) void mlpmm_kernel(
    const float* __restrict__ KEY, const float* __restrict__ QUERY,
    const float* __restrict__ B1a, const float* __restrict__ B2a, const float* __restrict__ B3a,
    const float* __restrict__ B1b, const float* __restrict__ B2b, const float* __restrict__ B3b,
    const unsigned short* __restrict__ sp,
    float* __restrict__ Ks, float* __restrict__ Qs, float* __restrict__ Wo)
{
  __shared__ unsigned short Xh[64][72], Xl[64][72];             // 18 KB
  __shared__ unsigned short Hsh[64][HSTRIDE], Hsl[64][HSTRIDE]; // 66 KB
  const int tid = threadIdx.x;
  const int w = tid >> 6;        // 0..7
  const int lane = tid & 63;
  const int l15 = lane & 15;
  const int quad = lane >> 4;

  const int g = blockIdx.x;
  const float* X;
  float* outp;
  int mulx, t0;
  const unsigned short* wb;
  const float *b1, *b2, *b3;
  if (g < 256)      { X = KEY;   outp = Ks; mulx = 1; t0 = g * 64;         wb = sp;          b1 = B1a; b2 = B2a; b3 = B3a; }
  else if (g < 512) { X = QUERY; outp = Qs; mulx = 1; t0 = (g - 256) * 64; wb = sp;          b1 = B1a; b2 = B2a; b3 = B3a; }
  else              { X = QUERY; outp = Wo; mulx = 0; t0 = (g - 512) * 64; wb = sp + 196608; b1 = B1b; b2 = B2b; b3 = B3b; }
  const unsigned short* W1h = wb;
  const unsigned short* W1l = wb + 16384;
  const unsigned short* W2h = wb + 32768;
  const unsigned short* W2l = wb + 98304;
  const unsigned short* W3h = wb + 163840;
  const unsigned short* W3l = wb + 180224;

  // ---- stage X tile (64 rows), split to bf16 h/l ----
  {
    const int t = tid >> 3;
    const int c = (tid & 7) * 8;
    float4 a = *(const float4*)&X[(size_t)(t0 + t) * 64 + c];
    float4 b = *(const float4*)&X[(size_t)(t0 + t) * 64 + c + 4];
    float v[8] = {a.x, a.y, a.z, a.w, b.x, b.y, b.z, b.w};
    unsigned short hs[8], ls[8];
#pragma unroll
    for (int e = 0; e < 8; ++e) splitbf(v[e], hs[e], ls[e]);
    uint4 uh = make_uint4(hs[0] | ((unsigned)hs[1] << 16), hs[2] | ((unsigned)hs[3] << 16),
                          hs[4] | ((unsigned)hs[5] << 16), hs[6] | ((unsigned)hs[7] << 16));
    uint4 ul = make_uint4(ls[0] | ((unsigned)ls[1] << 16), ls[2] | ((unsigned)ls[3] << 16),
                          ls[4] | ((unsigned)ls[5] << 16), ls[6] | ((unsigned)ls[7] << 16));
    *(uint4*)&Xh[t][c] = uh;
    *(uint4*)&Xl[t][c] = ul;
  }
  __syncthreads();

  // ---- layer 1: [64x64] x [64->256] ----
  {
    floatx4 acc[4][2];
#pragma unroll
    for (int nb = 0; nb < 2; ++nb) {
      const float bias = b1[(w * 2 + nb) * 16 + l15];
#pragma unroll
      for (int mb = 0; mb < 4; ++mb) acc[mb][nb] = (floatx4){bias, bias, bias, bias};
    }
#pragma unroll
    for (int kb = 0; kb < 2; ++kb) {
      bf16x8 Ah[4], Al[4];
#pragma unroll
      for (int mb = 0; mb < 4; ++mb) {
        Ah[mb] = *(const bf16x8*)&Xh[mb * 16 + l15][kb * 32 + quad * 8];
        Al[mb] = *(const bf16x8*)&Xl[mb * 16 + l15][kb * 32 + quad * 8];
      }
#pragma unroll
      for (int nb = 0; nb < 2; ++nb) {
        const int n0 = (w * 2 + nb) * 16;
        bf16x8 Bh = *(const bf16x8*)&W1h[(size_t)(n0 + l15) * 64 + kb * 32 + quad * 8];
        bf16x8 Bl = *(const bf16x8*)&W1l[(size_t)(n0 + l15) * 64 + kb * 32 + quad * 8];
#pragma unroll
        for (int mb = 0; mb < 4; ++mb) {
          acc[mb][nb] = __builtin_amdgcn_mfma_f32_16x16x32_bf16(Ah[mb], Bh, acc[mb][nb], 0, 0, 0);
          acc[mb][nb] = __builtin_amdgcn_mfma_f32_16x16x32_bf16(Al[mb], Bh, acc[mb][nb], 0, 0, 0);
          acc[mb][nb] = __builtin_amdgcn_mfma_f32_16x16x32_bf16(Ah[mb], Bl, acc[mb][nb], 0, 0, 0);
        }
      }
    }
#pragma unroll
    for (int mb = 0; mb < 4; ++mb)
#pragma unroll
      for (int nb = 0; nb < 2; ++nb) {
        const int col = (w * 2 + nb) * 16 + l15;
#pragma unroll
        for (int r = 0; r < 4; ++r) {
          const int row = mb * 16 + quad * 4 + r;
          float v = fmaxf(acc[mb][nb][r], 0.0f);
          unsigned short h, l;
          splitbf(v, h, l);
          Hsh[row][col] = h;
          Hsl[row][col] = l;
        }
      }
  }
  __syncthreads();

  // ---- layer 2: [64x256] x [256->256] ----
  {
    floatx4 acc2[4][2];
#pragma unroll
    for (int nb = 0; nb < 2; ++nb) {
      const float bias = b2[(w * 2 + nb) * 16 + l15];
#pragma unroll
      for (int mb = 0; mb < 4; ++mb) acc2[mb][nb] = (floatx4){bias, bias, bias, bias};
    }
#pragma unroll
    for (int kb = 0; kb < 8; ++kb) {
      bf16x8 Ah[4], Al[4];
#pragma unroll
      for (int mb = 0; mb < 4; ++mb) {
        Ah[mb] = *(const bf16x8*)&Hsh[mb * 16 + l15][kb * 32 + quad * 8];
        Al[mb] = *(const bf16x8*)&Hsl[mb * 16 + l15][kb * 32 + quad * 8];
      }
#pragma unroll
      for (int nb = 0; nb < 2; ++nb) {
        const int n0 = (w * 2 + nb) * 16;
        bf16x8 Bh = *(const bf16x8*)&W2h[(size_t)(n0 + l15) * 256 + kb * 32 + quad * 8];
        bf16x8 Bl = *(const bf16x8*)&W2l[(size_t)(n0 + l15) * 256 + kb * 32 + quad * 8];
#pragma unroll
        for (int mb = 0; mb < 4; ++mb) {
          acc2[mb][nb] = __builtin_amdgcn_mfma_f32_16x16x32_bf16(Ah[mb], Bh, acc2[mb][nb], 0, 0, 0);
          acc2[mb][nb] = __builtin_amdgcn_mfma_f32_16x16x32_bf16(Al[mb], Bh, acc2[mb][nb], 0, 0, 0);
          acc2[mb][nb] = __builtin_amdgcn_mfma_f32_16x16x32_bf16(Ah[mb], Bl, acc2[mb][nb], 0, 0, 0);
        }
      }
    }
    __syncthreads();
#pragma unroll
    for (int mb = 0; mb < 4; ++mb)
#pragma unroll
      for (int nb = 0; nb < 2; ++nb) {
        const int col = (w * 2 + nb) * 16 + l15;
#pragma unroll
        for (int r = 0; r < 4; ++r) {
          const int row = mb * 16 + quad * 4 + r;
          float v = fmaxf(acc2[mb][nb][r], 0.0f);
          unsigned short h, l;
          splitbf(v, h, l);
          Hsh[row][col] = h;
          Hsl[row][col] = l;
        }
      }
  }
  __syncthreads();

  // ---- layer 3: [64x256] x [256->64] ----
  {
    const int mp = (w >> 2) * 2;
    const int n0 = (w & 3) * 16;
    const float bias = b3[n0 + l15];
    floatx4 acc3[2];
#pragma unroll
    for (int m = 0; m < 2; ++m) acc3[m] = (floatx4){bias, bias, bias, bias};
#pragma unroll
    for (int kb = 0; kb < 8; ++kb) {
      bf16x8 Ah[2], Al[2];
#pragma unroll
      for (int m = 0; m < 2; ++m) {
        Ah[m] = *(const bf16x8*)&Hsh[(mp + m) * 16 + l15][kb * 32 + quad * 8];
        Al[m] = *(const bf16x8*)&Hsl[(mp + m) * 16 + l15][kb * 32 + quad * 8];
      }
      bf16x8 Bh = *(const bf16x8*)&W3h[(size_t)(n0 + l15) * 256 + kb * 32 + quad * 8];
      bf16x8 Bl = *(const bf16x8*)&W3l[(size_t)(n0 + l15) * 256 + kb * 32 + quad * 8];
#pragma unroll
      for (int m = 0; m < 2; ++m) {
        acc3[m] = __builtin_amdgcn_mfma_f32_16x16x32_bf16(Ah[m], Bh, acc3[m], 0, 0, 0);
        acc3[m] = __builtin_amdgcn_mfma_f32_16x16x32_bf16(Al[m], Bh, acc3[m], 0, 0, 0);
        acc3[m] = __builtin_amdgcn_mfma_f32_16x16x32_bf16(Ah[m], Bl, acc3[m], 0, 0, 0);
      }
    }
#pragma unroll
    for (int m = 0; m < 2; ++m)
#pragma unroll
      for (int r = 0; r < 4; ++r) {
        const int row = (mp + m) * 16 + quad * 4 + r;
        const int col = n0 + l15;
        float v = acc3[m][r];
        if (mulx) v *= (bf2f(Xh[row][col]) + bf2f(Xl[row][col]));
        outp[(size_t)(t0 + row) * 64 + col] = v;
      }
  }
}

// ---------------------------------------------------------------------------
// Flash attention over L1-distance scores, P.V on MFMA.
// Round-8: LDS trimmed to exactly 52 KB (psB stride 40->36) so 3 blocks/CU
// survive 2KB LDS-allocation rounding (round-7's 53KB blocked the 3rd block).
// Key split z=3 -> grid 1536 = 2 exact rounds of 768 resident blocks.
// Slices are uneven (4096/12 not a multiple of 32): slices 0..7 get 11
// iters (352 keys), slices 8..11 get 10 (320 keys).
// ---------------------------------------------------------------------------
template <bool PARTIAL>
__global__ __launch_bounds__(256, 3) void attn_kernel(
    const float* __restrict__ Ksg, const float* __restrict__ Qsg,
    const unsigned short* __restrict__ Vtg, const float* __restrict__ Wog,
    float* __restrict__ outp,
    float* __restrict__ Pm, float* __restrict__ Pl, float* __restrict__ PO)
{
  __shared__ float qsA[32 * FSTRIDE];              // 8704 B
  __shared__ float ksA[4][32 * FSTRIDE];           // 34816 B; reused as O-merge buf
  __shared__ unsigned short psB[4][32 * PSTRIDE];  // 9216 B; epilogue: m/l overlay
  __shared__ float abA[4][32];                     // 512 B
  // total 53248 B = 52 KB exactly -> 3 blocks/CU

  const int tid  = threadIdx.x;
  const int w    = tid >> 6;
  const int lane = tid & 63;
  const int lq   = lane >> 3;
  const int lk   = lane & 7;
  const int l15  = lane & 15;
  const int quad = lane >> 4;
  const int b    = blockIdx.y;
  const int qt   = blockIdx.x * 32;

  {
    const int row = tid >> 3;
    const int c0  = (tid & 7) * 2;
    const float4* Q4 = (const float4*)Qsg;
    float4 g0 = Q4[(size_t)(b * NQQ + qt + row) * 16 + c0];
    float4 g1 = Q4[(size_t)(b * NQQ + qt + row) * 16 + c0 + 1];
    *(float4*)&qsA[row * FSTRIDE + c0 * 4]     = g0;
    *(float4*)&qsA[row * FSTRIDE + c0 * 4 + 4] = g1;
  }
  __syncthreads();

  float m_i[4], l_i[4];
  floatx4 acc[2][4];
#pragma unroll
  for (int i = 0; i < 4; ++i) { m_i[i] = -3.0e38f; l_i[i] = 0.0f; }
#pragma unroll
  for (int mb = 0; mb < 2; ++mb)
#pragma unroll
    for (int nb = 0; nb < 4; ++nb)
#pragma unroll
      for (int r = 0; r < 4; ++r) acc[mb][nb][r] = 0.0f;

  int kstart, iters;
  if (PARTIAL) {
    const int slice = blockIdx.z * 4 + w;          // 0..11
    iters  = (slice < 8) ? 11 : 10;
    kstart = (slice < 8) ? slice * 352 : 2816 + (slice - 8) * 320;
  } else {
    iters  = 32;
    kstart = w * 1024;
  }
  const float4* K4 = (const float4*)Ksg;
  const float NEG_HALF_LOG2E = -0.72134752044448170f;  // -0.5*log2(e)

  const int krow = (lane >> 4);
  const int kci  = lane & 15;

  // V B-frag global base: lane (quad,l15) of frag nb reads
  // Vt[b][nb*16+l15][k=kstart+it*32+quad*8 .. +8] (16B, L2-resident).
  const unsigned short* vg0 = Vtg + ((size_t)b * 64 + l15) * NKK + kstart + quad * 8;

  float4 kpre[8];
  uint4 vtpre[4];
#pragma unroll
  for (int c = 0; c < 8; ++c)
    kpre[c] = K4[(size_t)(b * NKK + kstart + c * 4 + krow) * 16 + kci];
#pragma unroll
  for (int nb = 0; nb < 4; ++nb)
    vtpre[nb] = *(const uint4*)(vg0 + (size_t)nb * 16 * NKK);

  const floatx4* qb = (const floatx4*)&qsA[lq * FSTRIDE];
  const floatx4* kb = (const floatx4*)&ksA[w][lk * FSTRIDE];

  for (int it = 0; it < iters; ++it) {
    // ---- store prefetched K tile -> LDS (wave-private, no barrier) ----
#pragma unroll
    for (int c = 0; c < 8; ++c)
      *(float4*)&ksA[w][(c * 4 + krow) * FSTRIDE + kci * 4] = kpre[c];

    // ---- prefetch next K tile ----
    {
      const int itn = (it + 1 < iters) ? it + 1 : it;
#pragma unroll
      for (int c = 0; c < 8; ++c)
        kpre[c] = K4[(size_t)(b * NKK + kstart + itn * 32 + c * 4 + krow) * 16 + kci];
    }

    // ---- score: s[i][j] = sum_d |Ks[lk+8j] - Qs[lq+8i]|, 1.5 VALU/dim ----
    float s[4][4];
#pragma unroll
    for (int i = 0; i < 4; ++i)
#pragma unroll
      for (int j = 0; j < 4; ++j) s[i][j] = 0.0f;

#pragma unroll
    for (int dc = 0; dc < 16; ++dc) {
      floatx4 qv[4], kv[4];
#pragma unroll
      for (int i = 0; i < 4; ++i) qv[i] = qb[i * (8 * FSTRIDE4) + dc];
#pragma unroll
      for (int j = 0; j < 4; ++j) kv[j] = kb[j * (8 * FSTRIDE4) + dc];
#pragma unroll
      for (int i = 0; i < 4; ++i) {
        const floatx2 qlo = qv[i].lo, qhi = qv[i].hi;
#pragma unroll
        for (int j = 0; j < 4; ++j) {
          floatx2 d0 = pk_sub(qlo, kv[j].lo);
          floatx2 d1 = pk_sub(qhi, kv[j].hi);
          s[i][j] += __builtin_fabsf(d0.x);
          s[i][j] += __builtin_fabsf(d0.y);
          s[i][j] += __builtin_fabsf(d1.x);
          s[i][j] += __builtin_fabsf(d1.y);
        }
      }
    }

    // ---- online softmax (base-2); row max via min(s); l per-lane ----
    float a_row[4];
#pragma unroll
    for (int i = 0; i < 4; ++i) {
      float smin = fminf(fminf(s[i][0], s[i][1]), fminf(s[i][2], s[i][3]));
      smin = fminf(smin, __shfl_xor(smin, 1));
      smin = fminf(smin, __shfl_xor(smin, 2));
      smin = fminf(smin, __shfl_xor(smin, 4));
      const float tmax = smin * smin * NEG_HALF_LOG2E;
      const float mn = fmaxf(m_i[i], tmax);
      a_row[i] = fexp2(m_i[i] - mn);
      m_i[i] = mn;
      float ps = 0.0f;
#pragma unroll
      for (int j = 0; j < 4; ++j) {
        const float sv = s[i][j];
        const float e = fexp2(fmaf(sv * NEG_HALF_LOG2E, sv, -mn));
        ps += e;
        psB[w][(lq + 8 * i) * PSTRIDE + lk + 8 * j] = (unsigned short)(fbits(e) >> 16);
      }
      l_i[i] = fmaf(l_i[i], a_row[i], ps);
    }
    if (lk == 0) {
#pragma unroll
      for (int i = 0; i < 4; ++i) abA[w][lq + 8 * i] = a_row[i];
    }

    // ---- P.V on MFMA (B-frags straight from prefetched registers) ----
    {
      bf16x8 afrag[2];
#pragma unroll
      for (int mb = 0; mb < 2; ++mb)
        afrag[mb] = *(const bf16x8*)&psB[w][(mb * 16 + l15) * PSTRIDE + quad * 8];

      const floatx4 arv0 = *(const floatx4*)&abA[w][quad * 4];
      const floatx4 arv1 = *(const floatx4*)&abA[w][16 + quad * 4];

#pragma unroll
      for (int nb = 0; nb < 4; ++nb) {
        bf16x8 bfrag = __builtin_bit_cast(bf16x8, vtpre[nb]);
        acc[0][nb] *= arv0;
        acc[1][nb] *= arv1;
        acc[0][nb] = __builtin_amdgcn_mfma_f32_16x16x32_bf16(afrag[0], bfrag, acc[0][nb], 0, 0, 0);
        acc[1][nb] = __builtin_amdgcn_mfma_f32_16x16x32_bf16(afrag[1], bfrag, acc[1][nb], 0, 0, 0);
      }
    }

    // ---- prefetch next V tile (used next iter; full iter of latency slack) ----
    {
      const int itn = (it + 1 < iters) ? it + 1 : it;
#pragma unroll
      for (int nb = 0; nb < 4; ++nb)
        vtpre[nb] = *(const uint4*)(vg0 + (size_t)nb * 16 * NKK + itn * 32);
    }
  }

  // ---- epilogue: reduce l across lk; publish m,l (overlay on psB[w]) + O ----
#pragma unroll
  for (int i = 0; i < 4; ++i) {
    float l = l_i[i];
    l += __shfl_xor(l, 1);
    l += __shfl_xor(l, 2);
    l += __shfl_xor(l, 4);
    l_i[i] = l;
  }
  float* ovl = (float*)&psB[w][0];   // psB[w] dead after last P.V (wave-private)
  if (lk == 0) {
#pragma unroll
    for (int i = 0; i < 4; ++i) {
      ovl[lq + 8 * i]      = m_i[i];
      ovl[32 + lq + 8 * i] = l_i[i];
    }
  }
#pragma unroll
  for (int mb = 0; mb < 2; ++mb)
#pragma unroll
    for (int nb = 0; nb < 4; ++nb)
#pragma unroll
      for (int r = 0; r < 4; ++r)
        ksA[w][(mb * 16 + quad * 4 + r) * 64 + nb * 16 + l15] = acc[mb][nb][r];
  __syncthreads();

  {
    const int q = tid >> 3;
    const int dbase = (tid & 7) * 8;
    const float m0 = ((const float*)&psB[0][0])[q];
    const float m1 = ((const float*)&psB[1][0])[q];
    const float m2 = ((const float*)&psB[2][0])[q];
    const float m3 = ((const float*)&psB[3][0])[q];
    const float M = fmaxf(fmaxf(m0, m1), fmaxf(m2, m3));
    const float s0 = fexp2(m0 - M), s1 = fexp2(m1 - M);
    const float s2v = fexp2(m2 - M), s3 = fexp2(m3 - M);
    const float L = ((const float*)&psB[0][0])[32 + q] * s0 +
                    ((const float*)&psB[1][0])[32 + q] * s1 +
                    ((const float*)&psB[2][0])[32 + q] * s2v +
                    ((const float*)&psB[3][0])[32 + q] * s3;
    if (PARTIAL) {
      const size_t p = (size_t)(blockIdx.z * 4 + b) * 128 + blockIdx.x;
      if (dbase == 0) { Pm[p * 32 + q] = M; Pl[p * 32 + q] = L; }
      float* dst = PO + p * 2048 + q * 64 + dbase;
#pragma unroll
      for (int c = 0; c < 8; ++c) {
        const int d = dbase + c;
        dst[c] = s0 * ksA[0][q * 64 + d] + s1 * ksA[1][q * 64 + d] +
                 s2v * ksA[2][q * 64 + d] + s3 * ksA[3][q * 64 + d];
      }
    } else {
      const float rL = 1.0f / L;
      const size_t gbase = (size_t)(b * NQQ + qt + q) * 64 + dbase;
#pragma unroll
      for (int c = 0; c < 8; ++c) {
        const int d = dbase + c;
        float o = s0 * ksA[0][q * 64 + d] + s1 * ksA[1][q * 64 + d] +
                  s2v * ksA[2][q * 64 + d] + s3 * ksA[3][q * 64 + d];
        outp[gbase + c] = o * rL * Wog[gbase + c];
      }
    }
  }
}

// ---------------------------------------------------------------------------
// Merge the 3 key-split partials: out = sum_s(w_s O_s)/L * Wo.
// ---------------------------------------------------------------------------
__global__ __launch_bounds__(256) void amerge_kernel(
    const float* __restrict__ Pm, const float* __restrict__ Pl,
    const float* __restrict__ PO, const float* __restrict__ Wog,
    float* __restrict__ outp)
{
  const int tid = threadIdx.x;
  const int qt = blockIdx.x;
  const int b = blockIdx.y;
  const int q = tid >> 3;
  const int dbase = (tid & 7) * 8;
  size_t p[3];
  float mv[3], lv[3];
#pragma unroll
  for (int s = 0; s < 3; ++s) {
    p[s] = (size_t)(s * 4 + b) * 128 + qt;
    mv[s] = Pm[p[s] * 32 + q];
    lv[s] = Pl[p[s] * 32 + q];
  }
  const float M = fmaxf(fmaxf(mv[0], mv[1]), mv[2]);
  float wsum = 0.0f, wgt[3];
#pragma unroll
  for (int s = 0; s < 3; ++s) { wgt[s] = fexp2(mv[s] - M); wsum += wgt[s] * lv[s]; }
  const float rL = 1.0f / wsum;
  const size_t g = ((size_t)b * NQQ + qt * 32 + q) * 64 + dbase;
#pragma unroll
  for (int c = 0; c < 8; ++c) {
    float o = 0.0f;
#pragma unroll
    for (int s = 0; s < 3; ++s) o += wgt[s] * PO[p[s] * 2048 + q * 64 + dbase + c];
    outp[g + c] = o * rL * Wog[g + c];
  }
}

// ---------------------------------------------------------------------------
extern "C" void kernel_launch(void* const* d_in, const int* in_sizes, int n_in,
                              void* d_out, int out_size, void* d_ws, size_t ws_size,
                              hipStream_t stream) {
  (void)in_sizes; (void)n_in; (void)out_size;
  const float* KEY   = (const float*)d_in[0];
  const float* VALUE = (const float*)d_in[1];
  const float* QUERY = (const float*)d_in[2];
  const float* W1w = (const float*)d_in[3];
  const float* W1b = (const float*)d_in[4];
  const float* W2w = (const float*)d_in[5];
  const float* W2b = (const float*)d_in[6];
  const float* W3w = (const float*)d_in[7];
  const float* W3b = (const float*)d_in[8];
  const float* Wo1w = (const float*)d_in[9];
  const float* Wo1b = (const float*)d_in[10];
  const float* Wo2w = (const float*)d_in[11];
  const float* Wo2b = (const float*)d_in[12];
  const float* Wo3w = (const float*)d_in[13];
  const float* Wo3b = (const float*)d_in[14];

  float* ws = (float*)d_ws;
  const size_t tsz = (size_t)B_DIM * NKK * DD;  // 1,048,576 floats
  float* Ks = ws;
  float* Qs = ws + tsz;
  float* Wo = ws + 2 * tsz;
  unsigned short* Vtg = (unsigned short*)(ws + 3 * tsz);  // tsz ushorts (2 MB)
  unsigned short* sp  = Vtg + tsz;                        // 2x196608 ushorts
  float* Pm = ws + 3 * tsz + tsz / 2 + 196608;            // partial maxes (12x128x32)
  float* Pl = Pm + 49152;
  float* PO = Pl + 49152;                                 // 12x128x2048 floats
  float* outf = (float*)d_out;

  const size_t ws_need = (size_t)(3 * tsz + tsz / 2 + 196608 + 2 * 49152 + 3145728) * 4;
  const bool partial = ws_size >= ws_need;   // deterministic across calls

  wsplit_kernel<<<dim3(768), 256, 0, stream>>>(W1w, W2w, W3w, Wo1w, Wo2w, Wo3w, sp);
  vtrans_kernel<<<dim3(NKK / 64, B_DIM), 256, 0, stream>>>(VALUE, Vtg);
  mlpmm_kernel<<<dim3(768), 512, 0, stream>>>(
      KEY, QUERY, W1b, W2b, W3b, Wo1b, Wo2b, Wo3b, sp, Ks, Qs, Wo);
  if (partial) {
    attn_kernel<true><<<dim3(NQQ / 32, B_DIM, 3), 256, 0, stream>>>(
        Ks, Qs, Vtg, Wo, outf, Pm, Pl, PO);
    amerge_kernel<<<dim3(NQQ / 32, B_DIM), 256, 0, stream>>>(Pm, Pl, PO, Wo, outf);
  } else {
    attn_kernel<false><<<dim3(NQQ / 32, B_DIM, 1), 256, 0, stream>>>(
        Ks, Qs, Vtg, Wo, outf, Pm, Pl, PO);
  }
}